// Round 7
// baseline (4116.352 us; speedup 1.0000x reference)
//
#include <hip/hip_runtime.h>

#define BSZ 32
#define T 1024
#define D 512
#define H 512

// Recurrence blocking (per CU = per batch): thread j owns output rows
// (j&~3)+r, r=0..3, over column slice [(j&3)*128, (j&3)*128+128).
// -> 64 weight uint4/thread (256 f16 pairs): 48 uint4 in VGPRs (192 regs),
//    16 uint4 in LDS (4 rows x 4 groups x 512 thr x 16B = 128 KB).
// -> each h uint4 read feeds 16 dot2 (4 rows) : h LDS traffic / 4.
// -> partial sums reduced across the 4 col-slice lanes by __shfl_xor (no
//    LDS, no second barrier).
// Register math: 192 weight + ~36 working = ~228 live. 512 thr = 8 waves =
// 2 waves/EU -> VGPR cap 256. amdgpu_waves_per_eu(2,2) (NO __launch_bounds__,
// which round-4 showed clobbers it) removes the allocator's occupancy
// incentive to spill. Round-4 failure signature was VGPR=64 + 10MB scratch.

typedef _Float16 h2v __attribute__((ext_vector_type(2)));
union U32H2 { unsigned int u; h2v h; };

__device__ __forceinline__ unsigned int pack2(float x, float y) {
  U32H2 c; c.h = h2v{(_Float16)x, (_Float16)y}; return c.u;
}
__device__ __forceinline__ h2v uph(unsigned int u) { U32H2 c; c.u = u; return c.h; }

#if defined(__has_builtin)
#if __has_builtin(__builtin_amdgcn_fdot2)
#define HAVE_FDOT2 1
#endif
#endif

__device__ __forceinline__ float fdot2f(unsigned int w, unsigned int h, float acc) {
#ifdef HAVE_FDOT2
  return __builtin_amdgcn_fdot2(uph(w), uph(h), acc, false);
#else
  h2v wv = uph(w), hv = uph(h);
  acc = fmaf((float)wv[0], (float)hv[0], acc);
  return fmaf((float)wv[1], (float)hv[1], acc);
#endif
}

// Load 8 consecutive f32 weights -> uint4 of 4 packed f16 pairs.
__device__ __forceinline__ uint4 ldw(const float* p) {
  const float4 a = *(const float4*)p;
  const float4 b = *(const float4*)(p + 4);
  uint4 r;
  r.x = pack2(a.x, a.y); r.y = pack2(a.z, a.w);
  r.z = pack2(b.x, b.y); r.w = pack2(b.z, b.w);
  return r;
}

// ---------------------------------------------------------------------------
// Projection GEMM: C[m][n] = sum_d A[m][d] * W[n][d]   (fp32, 64x64 tile)
// ---------------------------------------------------------------------------
#define BM 64
#define BN 64
#define BK 32

__global__ __launch_bounds__(256) void gemm_proj(const float* __restrict__ A,
                                                 const float* __restrict__ W,
                                                 float* __restrict__ C) {
  __shared__ float As[BK][BM + 4];
  __shared__ float Bs[BK][BN + 4];
  const int bn = blockIdx.x * BN;
  const int bm = blockIdx.y * BM;
  const int tid = threadIdx.x;
  const int tx = tid & 15;
  const int ty = tid >> 4;
  float acc[4][4] = {};

  for (int k0 = 0; k0 < D; k0 += BK) {
    const int c = tid & 31;
    const int r0 = tid >> 5;
    #pragma unroll
    for (int i = 0; i < 8; ++i) {
      const int r = r0 + i * 8;
      As[c][r] = A[(size_t)(bm + r) * D + (k0 + c)];
      Bs[c][r] = W[(size_t)(bn + r) * D + (k0 + c)];
    }
    __syncthreads();
    #pragma unroll
    for (int kk = 0; kk < BK; ++kk) {
      const float4 av = *(const float4*)&As[kk][ty * 4];
      const float4 bv = *(const float4*)&Bs[kk][tx * 4];
      acc[0][0] = fmaf(av.x, bv.x, acc[0][0]);
      acc[0][1] = fmaf(av.x, bv.y, acc[0][1]);
      acc[0][2] = fmaf(av.x, bv.z, acc[0][2]);
      acc[0][3] = fmaf(av.x, bv.w, acc[0][3]);
      acc[1][0] = fmaf(av.y, bv.x, acc[1][0]);
      acc[1][1] = fmaf(av.y, bv.y, acc[1][1]);
      acc[1][2] = fmaf(av.y, bv.z, acc[1][2]);
      acc[1][3] = fmaf(av.y, bv.w, acc[1][3]);
      acc[2][0] = fmaf(av.z, bv.x, acc[2][0]);
      acc[2][1] = fmaf(av.z, bv.y, acc[2][1]);
      acc[2][2] = fmaf(av.z, bv.z, acc[2][2]);
      acc[2][3] = fmaf(av.z, bv.w, acc[2][3]);
      acc[3][0] = fmaf(av.w, bv.x, acc[3][0]);
      acc[3][1] = fmaf(av.w, bv.y, acc[3][1]);
      acc[3][2] = fmaf(av.w, bv.z, acc[3][2]);
      acc[3][3] = fmaf(av.w, bv.w, acc[3][3]);
    }
    __syncthreads();
  }
  #pragma unroll
  for (int i = 0; i < 4; ++i) {
    float4 o;
    o.x = acc[i][0]; o.y = acc[i][1]; o.z = acc[i][2]; o.w = acc[i][3];
    *(float4*)&C[(size_t)(bm + ty * 4 + i) * H + (bn + tx * 4)] = o;
  }
}

// ---- macros: 12 register uint4 groups per row, 4 LDS groups per row --------
#define DECL_ROW(r) \
  uint4 W##r##_0 = ldw(wr##r + 0),  W##r##_1 = ldw(wr##r + 8), \
        W##r##_2 = ldw(wr##r + 16), W##r##_3 = ldw(wr##r + 24), \
        W##r##_4 = ldw(wr##r + 32), W##r##_5 = ldw(wr##r + 40), \
        W##r##_6 = ldw(wr##r + 48), W##r##_7 = ldw(wr##r + 56), \
        W##r##_8 = ldw(wr##r + 64), W##r##_9 = ldw(wr##r + 72), \
        W##r##_10 = ldw(wr##r + 80), W##r##_11 = ldw(wr##r + 88);

// 16 dot2, row-interleaved so each accumulator is reused every 4 instrs.
#define DOTI(i) { const uint4 hq = hq4[(i)]; \
  a0 = fdot2f(W0_##i.x, hq.x, a0); a1 = fdot2f(W1_##i.x, hq.x, a1); \
  a2 = fdot2f(W2_##i.x, hq.x, a2); a3 = fdot2f(W3_##i.x, hq.x, a3); \
  a0 = fdot2f(W0_##i.y, hq.y, a0); a1 = fdot2f(W1_##i.y, hq.y, a1); \
  a2 = fdot2f(W2_##i.y, hq.y, a2); a3 = fdot2f(W3_##i.y, hq.y, a3); \
  a0 = fdot2f(W0_##i.z, hq.z, a0); a1 = fdot2f(W1_##i.z, hq.z, a1); \
  a2 = fdot2f(W2_##i.z, hq.z, a2); a3 = fdot2f(W3_##i.z, hq.z, a3); \
  a0 = fdot2f(W0_##i.w, hq.w, a0); a1 = fdot2f(W1_##i.w, hq.w, a1); \
  a2 = fdot2f(W2_##i.w, hq.w, a2); a3 = fdot2f(W3_##i.w, hq.w, a3); }

#define DOTL(q) { const uint4 hq = hq4[12 + (q)]; \
  const uint4 u0 = wlds[0][q][j], u1 = wlds[1][q][j]; \
  const uint4 u2 = wlds[2][q][j], u3 = wlds[3][q][j]; \
  a0 = fdot2f(u0.x, hq.x, a0); a1 = fdot2f(u1.x, hq.x, a1); \
  a2 = fdot2f(u2.x, hq.x, a2); a3 = fdot2f(u3.x, hq.x, a3); \
  a0 = fdot2f(u0.y, hq.y, a0); a1 = fdot2f(u1.y, hq.y, a1); \
  a2 = fdot2f(u2.y, hq.y, a2); a3 = fdot2f(u3.y, hq.y, a3); \
  a0 = fdot2f(u0.z, hq.z, a0); a1 = fdot2f(u1.z, hq.z, a1); \
  a2 = fdot2f(u2.z, hq.z, a2); a3 = fdot2f(u3.z, hq.z, a3); \
  a0 = fdot2f(u0.w, hq.w, a0); a1 = fdot2f(u1.w, hq.w, a1); \
  a2 = fdot2f(u2.w, hq.w, a2); a3 = fdot2f(u3.w, hq.w, a3); }

// ---------------------------------------------------------------------------
// Recurrence: one WG (512 thr) per batch. h = tanh(Z[t] + bias + Whh·h).
// ---------------------------------------------------------------------------
__global__ __attribute__((amdgpu_flat_work_group_size(512, 512),
                          amdgpu_waves_per_eu(2, 2)))
void rnn_rec(const float* __restrict__ Z,
             const float* __restrict__ Whh,
             const float* __restrict__ b_ih,
             const float* __restrict__ b_hh,
             float* __restrict__ Y,
             float* __restrict__ Hlast) {
  const int b = blockIdx.x;
  const int j = threadIdx.x;
  const int s = j & 3;            // column slice
  const int rowbase = j & ~3;     // 4 rows owned by this lane's group

  __shared__ __align__(16) unsigned int hb[2][H / 2];  // 2 KB (f16 pairs)
  __shared__ uint4 wlds[4][4][512];                    // 128 KB weight tail

  const float* wr0 = Whh + (size_t)(rowbase + 0) * H + (s << 7);
  const float* wr1 = Whh + (size_t)(rowbase + 1) * H + (s << 7);
  const float* wr2 = Whh + (size_t)(rowbase + 2) * H + (s << 7);
  const float* wr3 = Whh + (size_t)(rowbase + 3) * H + (s << 7);

  DECL_ROW(0) DECL_ROW(1) DECL_ROW(2) DECL_ROW(3)

  // LDS tail: groups 12..15 of each row.
  #pragma unroll
  for (int q = 0; q < 4; ++q) {
    wlds[0][q][j] = ldw(wr0 + 96 + 8 * q);
    wlds[1][q][j] = ldw(wr1 + 96 + 8 * q);
    wlds[2][q][j] = ldw(wr2 + 96 + 8 * q);
    wlds[3][q][j] = ldw(wr3 + 96 + 8 * q);
  }
  const float biasj = b_ih[j] + b_hh[j];
  if (j < H / 2) hb[0][j] = 0u;
  __syncthreads();

  const float* zb = Z + (size_t)b * T * H;
  float* yb = Y + (size_t)b * T * H;
  float hn = 0.0f;

  #pragma unroll 1
  for (int t = 0; t < T; ++t) {
    const float zt = zb[(size_t)t * H + j];  // issued first, consumed last
    const uint4* hq4 = ((const uint4*)hb[t & 1]) + (s << 4);
    float a0 = 0.f, a1 = 0.f, a2 = 0.f, a3 = 0.f;
    DOTI(0) DOTI(1) DOTI(2) DOTI(3) DOTI(4) DOTI(5)
    DOTI(6) DOTI(7) DOTI(8) DOTI(9) DOTI(10) DOTI(11)
    DOTL(0) DOTL(1) DOTL(2) DOTL(3)
    // Reduce across the 4 col-slice lanes (same wave, aligned groups of 4).
    a0 += __shfl_xor(a0, 1); a0 += __shfl_xor(a0, 2);
    a1 += __shfl_xor(a1, 1); a1 += __shfl_xor(a1, 2);
    a2 += __shfl_xor(a2, 1); a2 += __shfl_xor(a2, 2);
    a3 += __shfl_xor(a3, 1); a3 += __shfl_xor(a3, 2);
    const float dsum = (s == 0) ? a0 : (s == 1) ? a1 : (s == 2) ? a2 : a3;
    const float pre = zt + biasj + dsum;
    // tanh(x) = 1 - 2/(e^{2x}+1); exact at saturation.
    const float e = __expf(2.0f * pre);
    hn = 1.0f - 2.0f / (e + 1.0f);
    ((_Float16*)hb[(t + 1) & 1])[j] = (_Float16)hn;
    yb[(size_t)t * H + j] = hn;
    __syncthreads();
  }
  Hlast[(size_t)b * H + j] = hn;
}

// ---------------------------------------------------------------------------
extern "C" void kernel_launch(void* const* d_in, const int* in_sizes, int n_in,
                              void* d_out, int out_size, void* d_ws, size_t ws_size,
                              hipStream_t stream) {
  const float* x     = (const float*)d_in[0];
  const float* w_ih0 = (const float*)d_in[1];
  const float* w_hh0 = (const float*)d_in[2];
  const float* b_ih0 = (const float*)d_in[3];
  const float* b_hh0 = (const float*)d_in[4];
  const float* w_ih1 = (const float*)d_in[5];
  const float* w_hh1 = (const float*)d_in[6];
  const float* b_ih1 = (const float*)d_in[7];
  const float* b_hh1 = (const float*)d_in[8];

  float* out = (float*)d_out;
  float* Y  = out;                                  // y1 region [B*T*H]
  float* HL = out + (size_t)BSZ * T * H;            // hidden [2][B][H]
  float* Z  = (float*)d_ws;                         // scratch pre-activations

  const dim3 ggrid(H / BN, (BSZ * T) / BM);         // (8, 512)

  gemm_proj<<<ggrid, 256, 0, stream>>>(x, w_ih0, Z);
  rnn_rec<<<BSZ, 512, 0, stream>>>(Z, w_hh0, b_ih0, b_hh0, Y, HL);

  gemm_proj<<<ggrid, 256, 0, stream>>>(Y, w_ih1, Z);
  rnn_rec<<<BSZ, 512, 0, stream>>>(Z, w_hh1, b_ih1, b_hh1, Y, HL + (size_t)BSZ * H);
}